// Round 12
// baseline (30.876 us; speedup 1.0000x reference)
//
#include <hip/hip_runtime.h>

// Chamfer loss: B=8, V=4, N=2048, D=3 fp32.
// final = per_view[0] + sum_v per_view[v]; per_view = mean_b(cham_x + cham_y)
// => weight per (b,v,dir) job = ((v==0)?2:1)/8.
//
// R17 = R14 (17.18us, proven) + fused final via LAST-BLOCK ELECTION:
//  - kernel_launch: hipMemsetAsync(cnt,0,4) node (re-zeroed EVERY replay ->
//    poison-proof) + one kernel. R15 (grid.sync) hung the graph; R16
//    (atomicAdd into out) broke launch idempotency -- out must be STORED.
//  - each block stores bsum[bid] (plain), t0 does agent-scope ACQ_REL
//    fetch_add on cnt; ticket==511 elects the last block, whose acquire
//    syncs-with all prior releases (cross-XCD visibility incl. cache inv).
//  - last block reduces bsum[512] in chamfer_final's exact order -> out[0]
//    plain store => bitwise-deterministic, idempotent across replays.
//
// R14's tail: LDS transpose-reduce in the dead yf buffer ([64][33] f32 pane
// per wave, bank (row+col)%32 conflict-free) instead of the 160-swizzle
// butterfly (-3us vs R7).
//
// Math (absmax 0.0 across R7-R14): dot(x,y) via 4-term bf16 split inside
// mfma_f32_32x32x16_bf16; -0.5|y|^2 folded as fp32-accurate (wh,wl) K-slots
// vs A=1.0. t = x.y - 0.5|y|^2; min d2 <=> max t; d2 = |x|^2 - 2t (|x|^2 fp32).
// K-slot map (A,B share it): k0-2 h*h, k3-5 h*l, k6-8 l*h, k9-10 1*(wh,wl),
// k11-13 l*l, k14-15 zero. C layout: col=lane&31, row=(j&3)+8*(j>>2)+4*(lane>>5).

#define B_ 8
#define V_ 4
#define N_ 2048
#define JOBS 64
#define RPB 256                       // rows per block
#define GRID_ (JOBS * (N_ / RPB))     // 512
#define CHUNK 512                     // cols per LDS chunk
#define NCHUNK (N_ / CHUNK)           // 4
#define CPITCH 24                     // ushorts per col (48 B): 16 data + 8 pad

typedef short bf16x8 __attribute__((ext_vector_type(8)));
typedef float f32x16 __attribute__((ext_vector_type(16)));

__device__ __forceinline__ unsigned short f2bf(float f) {
  union { float f; unsigned u; } v; v.f = f;
  const unsigned r = v.u + 0x7fffu + ((v.u >> 16) & 1u);  // RNE, same as v_cvt
  return (unsigned short)(r >> 16);
}
__device__ __forceinline__ float bf2f(unsigned short h) {
  union { unsigned u; float f; } v; v.u = ((unsigned)h) << 16;
  return v.f;
}

__device__ __forceinline__ void pack_col(float y0, float y1, float y2,
                                         unsigned short* dst) {
  const unsigned short h0 = f2bf(y0), h1 = f2bf(y1), h2 = f2bf(y2);
  const unsigned short l0 = f2bf(y0 - bf2f(h0));
  const unsigned short l1 = f2bf(y1 - bf2f(h1));
  const unsigned short l2 = f2bf(y2 - bf2f(h2));
  const float w = -0.5f * fmaf(y0, y0, fmaf(y1, y1, y2 * y2));
  const unsigned short wh = f2bf(w);
  const unsigned short wl = f2bf(w - bf2f(wh));
  bf16x8 b0, b1;
  b0[0] = (short)h0; b0[1] = (short)h1; b0[2] = (short)h2;   // k0-2
  b0[3] = (short)l0; b0[4] = (short)l1; b0[5] = (short)l2;   // k3-5
  b0[6] = (short)h0; b0[7] = (short)h1;                      // k6-7
  b1[0] = (short)h2;                                         // k8
  b1[1] = (short)wh; b1[2] = (short)wl;                      // k9-10
  b1[3] = (short)l0; b1[4] = (short)l1; b1[5] = (short)l2;   // k11-13
  b1[6] = 0; b1[7] = 0;                                      // k14-15
  *(bf16x8*)(dst) = b0;        // ds_write_b128, 16B-aligned (pitch 48)
  *(bf16x8*)(dst + 8) = b1;
}

__device__ __forceinline__ void stage_chunk(const float* __restrict__ yb,
                                            unsigned short* __restrict__ dstbuf,
                                            int ch, int t) {
  const int c0 = ch * CHUNK + t * 2;                  // 2 cols per thread
  const float2* yp2 = (const float2*)(yb + (size_t)c0 * 3);  // 8B-aligned
  const float2 u0 = yp2[0], u1 = yp2[1], u2 = yp2[2];
  unsigned short* dst = dstbuf + (size_t)(t * 2) * CPITCH;
  pack_col(u0.x, u0.y, u1.x, dst);
  pack_col(u1.y, u2.x, u2.y, dst + CPITCH);
}

__global__ __launch_bounds__(256, 2) void chamfer_main(
    const float* __restrict__ X, const float* __restrict__ T,
    float* __restrict__ bsum, unsigned int* __restrict__ cnt,
    float* __restrict__ out) {
  __shared__ unsigned short yf[2][CHUNK * CPITCH];  // 2 x 24 KB
  __shared__ float red4[4];
  __shared__ int lastflag;

  // XCD swizzle: physical p -> XCD p&7; XCD x owns logical [x*64,(x+1)*64)
  // = 8 consecutive jobs (y/x panels L2-resident per XCD).
  const int p = blockIdx.x;
  const int bid = (p & 7) * (GRID_ / 8) + (p >> 3);
  const int job = bid >> 3;          // [0,64): 8 blocks per job
  const int rc  = bid & 7;           // row-chunk of 256
  const int pair = job >> 1;
  const int dir  = job & 1;          // 0: rows=X cols=T (cham_x), 1: swapped
  const float* xb = (dir ? T : X) + (size_t)pair * N_ * 3;
  const float* yb = (dir ? X : T) + (size_t)pair * N_ * 3;
  const int t = threadIdx.x;
  const int lane = t & 63;
  const int wv = t >> 6;
  const int lr = lane & 31;          // A-row / B-col within tile
  const int g  = lane >> 5;          // K-group (which 8 k-slots this lane feeds)

  // ---- A fragments: this wave's 64 rows = 2 row-tiles of 32 ----
  bf16x8 afrag[2];
  float xn2[2];
  const int rbase = rc * RPB + wv * 64;
#pragma unroll
  for (int rt = 0; rt < 2; ++rt) {
    const int r = rbase + rt * 32 + lr;
    const float x0 = xb[r * 3 + 0], x1 = xb[r * 3 + 1], x2 = xb[r * 3 + 2];
    xn2[rt] = fmaf(x0, x0, fmaf(x1, x1, x2 * x2));
    const unsigned short h0 = f2bf(x0), h1 = f2bf(x1), h2 = f2bf(x2);
    const unsigned short l0 = f2bf(x0 - bf2f(h0));
    const unsigned short l1 = f2bf(x1 - bf2f(h1));
    const unsigned short l2 = f2bf(x2 - bf2f(h2));
    const unsigned short ONE = 0x3F80;  // bf16 1.0
    bf16x8 a;
    if (g == 0) {  // k0-7
      a[0] = (short)h0; a[1] = (short)h1; a[2] = (short)h2;
      a[3] = (short)h0; a[4] = (short)h1; a[5] = (short)h2;
      a[6] = (short)l0; a[7] = (short)l1;
    } else {       // k8-15
      a[0] = (short)l2; a[1] = (short)ONE; a[2] = (short)ONE;
      a[3] = (short)l0; a[4] = (short)l1; a[5] = (short)l2;
      a[6] = 0; a[7] = 0;
    }
    afrag[rt] = a;
  }

  f32x16 r0, r1;
#pragma unroll
  for (int j = 0; j < 16; ++j) { r0[j] = -1e30f; r1[j] = -1e30f; }

  stage_chunk(yb, yf[0], 0, t);
  __syncthreads();

  for (int ch = 0; ch < NCHUNK; ++ch) {
    if (ch + 1 < NCHUNK)                       // overlap: fill other buffer
      stage_chunk(yb, yf[(ch + 1) & 1], ch + 1, t);
    const unsigned short* yfb = yf[ch & 1];
#pragma unroll
    for (int pr = 0; pr < CHUNK / 64; ++pr) {  // 8 col-tile pairs
      const unsigned short* pa = yfb + (size_t)(pr * 64 + lr) * CPITCH + g * 8;
      const bf16x8 bA = *(const bf16x8*)pa;                    // ds_read_b128
      const bf16x8 bB = *(const bf16x8*)(pa + 32 * CPITCH);
      const f32x16 d00 =
          __builtin_amdgcn_mfma_f32_32x32x16_bf16(afrag[0], bA, (f32x16){}, 0, 0, 0);
      const f32x16 d10 =
          __builtin_amdgcn_mfma_f32_32x32x16_bf16(afrag[1], bA, (f32x16){}, 0, 0, 0);
      const f32x16 d01 =
          __builtin_amdgcn_mfma_f32_32x32x16_bf16(afrag[0], bB, (f32x16){}, 0, 0, 0);
      const f32x16 d11 =
          __builtin_amdgcn_mfma_f32_32x32x16_bf16(afrag[1], bB, (f32x16){}, 0, 0, 0);
#pragma unroll
      for (int j = 0; j < 16; ++j) {           // 2 new values per v_max3
        r0[j] = fmaxf(fmaxf(r0[j], d00[j]), d01[j]);
        r1[j] = fmaxf(fmaxf(r1[j], d10[j]), d11[j]);
      }
    }
    __syncthreads();  // writes for ch+1 visible; reads of ch done before reuse
  }

  // ---- tail (R14): LDS transpose-reduce in the dead yf buffer. Per-wave
  // pane [64 rows][33 f32]: value (rt,j) of lane -> row rt*32+(j&3)+8*(j>>2)
  // +4*g, col lr. Bank = (row+col)%32: conflict-free writes AND reads.
  // Column 32 holds |x|^2 per row. One barrier, then lane l folds row l.
  float* tw = ((float*)&yf[0][0]) + wv * (64 * 33);  // 8448 B/wave
#pragma unroll
  for (int rt = 0; rt < 2; ++rt) {
#pragma unroll
    for (int j = 0; j < 16; ++j) {
      const int rl = rt * 32 + (j & 3) + 8 * (j >> 2) + 4 * g;
      tw[rl * 33 + lr] = rt ? r1[j] : r0[j];
    }
    // lanes l and l+32 share lr -> same row, same xn2 value: benign dup write
    tw[(rt * 32 + lr) * 33 + 32] = xn2[rt];
  }
  __syncthreads();

  // lane l owns row l of its wave's pane: fold 32 col-maxes + xn2.
  float mx = -1e30f;
#pragma unroll
  for (int c = 0; c < 32; ++c) mx = fmaxf(mx, tw[lane * 33 + c]);
  const float d = fmaf(-2.0f, mx, tw[lane * 33 + 32]);  // min d2 for row

  const int v_ = pair & (V_ - 1);
  float acc = d * (((v_ == 0) ? 2.0f : 1.0f) * (1.0f / (float)B_));
#pragma unroll
  for (int o = 32; o > 0; o >>= 1) acc += __shfl_down(acc, o, 64);
  if (lane == 0) red4[wv] = acc;
  __syncthreads();

  // ---- fused final (NEW vs R14): last-block election ----
  if (t == 0) {
    bsum[bid] = (red4[0] + red4[1]) + (red4[2] + red4[3]);  // plain store
    // ACQ_REL RMW: release publishes our bsum store; the last ticket's
    // acquire syncs-with all 511 prior releases (cross-XCD cache inv).
    const unsigned int ticket = __hip_atomic_fetch_add(
        cnt, 1u, __ATOMIC_ACQ_REL, __HIP_MEMORY_SCOPE_AGENT);
    lastflag = (ticket == GRID_ - 1) ? 1 : 0;
  }
  __syncthreads();
  if (lastflag) {
    // exact chamfer_final ordering -> bitwise-identical result every replay
    float v = bsum[t] + bsum[t + 256];
#pragma unroll
    for (int o = 32; o > 0; o >>= 1) v += __shfl_down(v, o, 64);
    if (lane == 0) red4[wv] = v;
    __syncthreads();
    if (t == 0) out[0] = (red4[0] + red4[1]) + (red4[2] + red4[3]);
  }
}

extern "C" void kernel_launch(void* const* d_in, const int* in_sizes, int n_in,
                              void* d_out, int out_size, void* d_ws, size_t ws_size,
                              hipStream_t stream) {
  const float* X = (const float*)d_in[0];
  const float* T = (const float*)d_in[1];
  float* out = (float*)d_out;
  unsigned int* cnt = (unsigned int*)d_ws;            // offset 0: ticket counter
  float* bsum = (float*)((char*)d_ws + 16);           // 512 floats

  // Re-zero the counter EVERY launch (d_ws is re-poisoned between replays;
  // memset is stream-ordered and graph-capturable; not in the G9 ban list).
  hipMemsetAsync(cnt, 0, 4, stream);
  chamfer_main<<<GRID_, 256, 0, stream>>>(X, T, bsum, cnt, out);
}